// Round 5
// baseline (325.173 us; speedup 1.0000x reference)
//
#include <hip/hip_runtime.h>
#include <hip/hip_bf16.h>
#include <hip/hip_cooperative_groups.h>

namespace cg = cooperative_groups;

#define LATN 512
#define FINN 256
#define FOUTN 256
#define NB 16
#define HH 64
#define WW 64

typedef __attribute__((ext_vector_type(8))) short bf16x8;
typedef __attribute__((ext_vector_type(4))) float f32x4;
typedef __attribute__((ext_vector_type(4))) int i32x4;

// ------- workspace byte offsets -------
#define WS_ZERO   0           // 256 B
#define WS_MW2    4096        // 256*256*4 = 262144
#define WS_DCO    266240      // 16*256*4  = 16384
#define WS_SNORM  282624      // 16*256*4  = 16384
#define WS_WFMT   299008      // 4*294912  = 1179648
#define WS_XM     1478656     // 16*2097152 = 33554432
// style ping-pong buffers ALIAS the xm region (dead before xcvt phase writes xm):
#define WS_HA     (WS_XM)            // 16*512*4
#define WS_HB     (WS_XM + 32768)    // 16*512*4
#define WS_STY    (WS_XM + 65536)    // 16*256*4
// xm layout  : [b][chunk(8)][pos(4096)][slot(4)] granules of 16B (8 bf16 ch), slot = iq ^ sigma(h,w)
// wfmt layout: [obi(4)][chunk(8)][tap(9)][ol(64)][slot(4)] granules, slot = iq ^ ((ol>>1)&3)

// ================= fused cooperative prep kernel =================
// grid = 256 blocks x 256 threads. Phases:
// A: weight prep (block=o)  B: 4 MLP layers  C: final linear  D: inf-norm
// E: dcoef  F: xcvt (4 (b,h) slices per block)
__global__ __launch_bounds__(256) void prep_kernel(
    const float* __restrict__ x, const float* __restrict__ lat,
    const float* __restrict__ weight, const float* __restrict__ wsm,
    const float* __restrict__ bsm, const float* __restrict__ wf,
    const float* __restrict__ bf,
    __hip_bfloat16* __restrict__ wfmt, float* __restrict__ mw2,
    float* __restrict__ snorm, float* __restrict__ dco,
    float* __restrict__ zerobuf, char* __restrict__ xm,
    float* __restrict__ hA, float* __restrict__ hB, float* __restrict__ sty) {
    cg::grid_group gg = cg::this_grid();
    __shared__ float red[256];
    __shared__ float lin[512];
    __shared__ float tile[64][65];
    int bi = blockIdx.x, t = threadIdx.x;

    // ---- phase A: weight prep ----
    {
        int o = bi;
        if (o == 0 && t < 64) zerobuf[t] = 0.f;
        const float* wrow = weight + ((size_t)o * FINN + t) * 9;
        float wv[9];
        float mx = 0.f;
        #pragma unroll
        for (int k = 0; k < 9; ++k) { wv[k] = wrow[k]; mx = fmaxf(mx, fabsf(wv[k])); }
        red[t] = mx;
        __syncthreads();
        for (int k = 128; k > 0; k >>= 1) {
            if (t < k) red[t] = fmaxf(red[t], red[t + k]);
            __syncthreads();
        }
        float scale = (1.0f / 48.0f) / red[0];
        int obi = o >> 6, ol = o & 63, ch = t >> 5, il = t & 31;
        int slot = (il >> 3) ^ ((ol >> 1) & 3);
        char* basep = (char*)wfmt + (size_t)obi * 294912 + (size_t)ch * 36864
                    + (size_t)ol * 64 + slot * 16 + (il & 7) * 2;
        float s2 = 0.f;
        #pragma unroll
        for (int tap = 0; tap < 9; ++tap) {
            float m = wv[tap] * scale;
            s2 += m * m;
            *(__hip_bfloat16*)(basep + tap * 4096) = __float2bfloat16(m);
        }
        mw2[(size_t)o * FINN + t] = s2;
    }

    // ---- phase B: 4 EqualLinear + LeakyReLU layers ----
    const float eq = 0.044194173824159216f;  // 1/sqrt(512)
    {
        int b = bi & 15, j0 = (bi >> 4) * 32;
        const float* in = lat;
        float* out = hA;
        for (int l = 0; l < 4; ++l) {
            __syncthreads();
            lin[t] = in[(size_t)b * 512 + t];
            lin[t + 256] = in[(size_t)b * 512 + 256 + t];
            __syncthreads();
            int jl = t >> 3, kl = t & 7;
            int j = j0 + jl;
            const float4* wr = (const float4*)(wsm + (size_t)l * 262144 + (size_t)j * 512);
            const float4* iv = (const float4*)lin;
            float sum = 0.f;
            #pragma unroll 4
            for (int kb = kl; kb < 128; kb += 8) {
                float4 wv = wr[kb], vv = iv[kb];
                sum += wv.x * vv.x + wv.y * vv.y + wv.z * vv.z + wv.w * vv.w;
            }
            sum += __shfl_xor(sum, 1, 8);
            sum += __shfl_xor(sum, 2, 8);
            sum += __shfl_xor(sum, 4, 8);
            if (kl == 0) {
                float v = sum * eq + bsm[l * 512 + j];
                out[(size_t)b * 512 + j] = (v < 0.f) ? 0.2f * v : v;
            }
            gg.sync();
            in = out;
            out = (l & 1) ? hA : hB;
        }
    }
    // ---- phase C: final linear 512 -> 256 (hB -> sty) ----
    {
        int b = bi & 15, j0 = (bi >> 4) * 16;
        lin[t] = hB[(size_t)b * 512 + t];
        lin[t + 256] = hB[(size_t)b * 512 + 256 + t];
        __syncthreads();
        int jl = t >> 4, kl = t & 15;
        int j = j0 + jl;
        const float4* wr = (const float4*)(wf + (size_t)j * 512);
        const float4* iv = (const float4*)lin;
        float sum = 0.f;
        #pragma unroll 4
        for (int kb = kl; kb < 128; kb += 16) {
            float4 wv = wr[kb], vv = iv[kb];
            sum += wv.x * vv.x + wv.y * vv.y + wv.z * vv.z + wv.w * vv.w;
        }
        #pragma unroll
        for (int off = 8; off >= 1; off >>= 1) sum += __shfl_xor(sum, off, 16);
        if (kl == 0) sty[(size_t)b * 256 + j] = sum + bf[j];
    }
    gg.sync();
    // ---- phase D: inf-norm per b ----
    if (bi < 16) {
        int b = bi;
        float v = sty[(size_t)b * 256 + t];
        red[t] = fabsf(v);
        __syncthreads();
        for (int k = 128; k > 0; k >>= 1) {
            if (t < k) red[t] = fmaxf(red[t], red[t + k]);
            __syncthreads();
        }
        snorm[(size_t)b * 256 + t] = v / red[0];
    }
    gg.sync();
    // ---- phase E: dcoef ----
    {
        int b = bi & 15, o0 = (bi >> 4) * 16;
        float sv = snorm[(size_t)b * 256 + t];
        __syncthreads();
        lin[t] = sv * sv;
        __syncthreads();
        int ol = t >> 4, kl = t & 15;
        int o = o0 + ol;
        const float4* m2 = (const float4*)(mw2 + (size_t)o * 256);
        const float4* sq = (const float4*)lin;
        float sum = 0.f;
        #pragma unroll
        for (int kb = kl; kb < 64; kb += 16) {
            float4 a = m2[kb], xq = sq[kb];
            sum += a.x * xq.x + a.y * xq.y + a.z * xq.z + a.w * xq.w;
        }
        #pragma unroll
        for (int off = 8; off >= 1; off >>= 1) sum += __shfl_xor(sum, off, 16);
        if (kl == 0) dco[(size_t)b * 256 + o] = rsqrtf(sum + 1e-8f);
    }
    // ---- phase F: xcvt, 4 (b,h) slices per block ----
    {
        int wl_ = t & 63, ig = t >> 6;
        for (int s = 0; s < 4; ++s) {
            int id = bi * 4 + s;
            int b = id >> 6, h = id & 63;
            char* xmb = xm + (size_t)b * 2097152;
            for (int icb = 0; icb < 4; ++icb) {
                __syncthreads();
                #pragma unroll
                for (int p = 0; p < 16; ++p) {
                    int i_l = p * 4 + ig;
                    int i = icb * 64 + i_l;
                    tile[i_l][wl_] = x[((size_t)(b * FINN + i)) * 4096 + h * 64 + wl_]
                                     * snorm[(size_t)b * FINN + i];
                }
                __syncthreads();
                #pragma unroll
                for (int rep = 0; rep < 2; ++rep) {
                    int g = rep * 256 + t;
                    int w = g >> 3, q8 = g & 7;
                    int chunk = icb * 2 + (q8 >> 2), iq = q8 & 3;
                    int slot = iq ^ (((h + 1) + ((w + 1) >> 1)) & 3);
                    short tmp[8];
                    #pragma unroll
                    for (int j = 0; j < 8; ++j) {
                        __hip_bfloat16 hb = __float2bfloat16(tile[q8 * 8 + j][w]);
                        tmp[j] = *(short*)&hb;
                    }
                    char* dst = xmb + (size_t)chunk * 262144
                              + (size_t)(h * 64 + w) * 64 + slot * 16;
                    *(bf16x8*)dst = *(bf16x8*)tmp;
                }
            }
        }
    }
}

// ================= global_load_lds helper =================
__device__ __forceinline__ void gl_lds16(const void* g, void* l) {
    __builtin_amdgcn_global_load_lds(
        (const __attribute__((address_space(1))) unsigned int*)g,
        (__attribute__((address_space(3))) unsigned int*)l, 16, 0, 0);
}

// ================= MFMA conv, double-buffered 2-phase schedule =================
// grid (8 htile, 4 obi, 16 b), 512 threads (8 waves).
__global__ __launch_bounds__(512, 2) void mconv_kernel(
    const char* __restrict__ xm, const char* __restrict__ wfmt,
    const float* __restrict__ dco, const float* __restrict__ zerobuf,
    float* __restrict__ y) {
    __shared__ char xs[2][42240];   // 10 rows x 66 cols x 64B, swizzled slots
    __shared__ char wl[2][36864];   // [tap 9][o 64][slot 4] granules

    int t = threadIdx.x;
    int lane = t & 63;
    int wid = t >> 6;
    int h0 = blockIdx.x * 8;
    int obi = blockIdx.y;
    int b = blockIdx.z;

    // zero halo columns (c=0, c=65) in BOTH buffers; never overwritten by staging
    if (t < 160) {
        int bufi = t / 80, u = t % 80;
        int r = u >> 3, sub = u & 7;
        int col = (sub >> 2) * 65, slot = sub & 3;
        *(i32x4*)(xs[bufi] + ((r * 66 + col) * 4 + slot) * 16) = (i32x4){0, 0, 0, 0};
    }

    // x staging: 40 issues/chunk (10 rows x 4 quarters), 5 per wave
    const char* xmb = xm + (size_t)b * 2097152;
    const char* xsrc[5];
    unsigned xinc[5];
    unsigned xdst[5];
    #pragma unroll
    for (int q = 0; q < 5; ++q) {
        int idx = wid * 5 + q;
        int r = idx >> 2, quarter = idx & 3;
        int gh = h0 - 1 + r;
        bool v = (gh >= 0) && (gh < HH);
        xsrc[q] = v ? xmb + (size_t)(gh * 64 + quarter * 16) * 64 + lane * 16
                    : (const char*)zerobuf;
        xinc[q] = v ? 262144u : 0u;
        xdst[q] = (unsigned)((r * 66 + 1) * 64 + quarter * 1024);
    }
    const char* wlane = wfmt + (size_t)obi * 294912 + lane * 16;

    f32x4 acc[4][4] = {};
    int l15 = lane & 15, lg = lane >> 4;
    int wfrag = l15 * 64 + ((lg ^ ((l15 >> 1) & 3)) << 4);

    // ---- prologue: stage chunk 0 into buf 0 ----
    #pragma unroll
    for (int q = 0; q < 5; ++q) {
        gl_lds16(xsrc[q], xs[0] + xdst[q]);
        xsrc[q] += xinc[q];
    }
    #pragma unroll
    for (int q = 0; q < 5; ++q) {
        int idx = wid + q * 8;
        if (idx < 36) gl_lds16(wlane + idx * 1024, wl[0] + idx * 1024);
    }
    wlane += 36864;
    asm volatile("s_waitcnt vmcnt(0)" ::: "memory");
    __builtin_amdgcn_s_barrier();
    __builtin_amdgcn_sched_barrier(0);

    for (int ch = 0; ch < 8; ++ch) {
        int cur = ch & 1;
        // issue next-chunk stages into the other buffer (loads stay in flight
        // across the whole compute phase; drained AFTER compute)
        if (ch < 7) {
            #pragma unroll
            for (int q = 0; q < 5; ++q) {
                gl_lds16(xsrc[q], xs[cur ^ 1] + xdst[q]);
                xsrc[q] += xinc[q];
            }
            #pragma unroll
            for (int q = 0; q < 5; ++q) {
                int idx = wid + q * 8;
                if (idx < 36) gl_lds16(wlane + idx * 1024, wl[cur ^ 1] + idx * 1024);
            }
            wlane += 36864;
        }
        const char* xsb = xs[cur];
        const char* wlb = wl[cur];
        __builtin_amdgcn_s_setprio(1);
        #pragma unroll
        for (int kh = 0; kh < 3; ++kh) {
            #pragma unroll
            for (int kw = 0; kw < 3; ++kw) {
                int tap = kh * 3 + kw;
                int pos0 = (wid + kh) * 66 + kw + l15;
                int xb_off = pos0 * 64 + ((lg ^ ((pos0 >> 1) & 3)) << 4);
                bf16x8 bfr[4];
                #pragma unroll
                for (int nt = 0; nt < 4; ++nt)
                    bfr[nt] = *(const bf16x8*)(xsb + xb_off + nt * 1024);
                #pragma unroll
                for (int mt = 0; mt < 4; ++mt) {
                    bf16x8 af = *(const bf16x8*)(wlb + tap * 4096 + mt * 1024 + wfrag);
                    #pragma unroll
                    for (int nt = 0; nt < 4; ++nt)
                        acc[mt][nt] = __builtin_amdgcn_mfma_f32_16x16x32_bf16(
                            af, bfr[nt], acc[mt][nt], 0, 0, 0);
                }
            }
        }
        __builtin_amdgcn_s_setprio(0);
        // drain this iteration's stage-writes (they had the full compute
        // phase to land), then release the buffer we just read
        asm volatile("s_waitcnt vmcnt(0)" ::: "memory");
        __builtin_amdgcn_s_barrier();
        __builtin_amdgcn_sched_barrier(0);
    }

    // epilogue: demod + store
    const float* dcb = dco + (size_t)b * FOUTN + obi * 64;
    float* yb = y + (((size_t)b * FOUTN + obi * 64) * HH + (h0 + wid)) * WW;
    #pragma unroll
    for (int mt = 0; mt < 4; ++mt) {
        #pragma unroll
        for (int j = 0; j < 4; ++j) {
            int o_l = mt * 16 + lg * 4 + j;
            float d = dcb[o_l];
            #pragma unroll
            for (int nt = 0; nt < 4; ++nt)
                yb[(size_t)o_l * 4096 + nt * 16 + l15] = acc[mt][nt][j] * d;
        }
    }
}

extern "C" void kernel_launch(void* const* d_in, const int* in_sizes, int n_in,
                              void* d_out, int out_size, void* d_ws, size_t ws_size,
                              hipStream_t stream) {
    const float* x      = (const float*)d_in[0];
    const float* lat    = (const float*)d_in[1];
    const float* weight = (const float*)d_in[2];
    const float* wsm    = (const float*)d_in[3];
    const float* bsm    = (const float*)d_in[4];
    const float* wff    = (const float*)d_in[5];
    const float* bff    = (const float*)d_in[6];
    float* y = (float*)d_out;

    char* base = (char*)d_ws;
    float* zerobuf = (float*)(base + WS_ZERO);
    float* mw2     = (float*)(base + WS_MW2);
    float* dco     = (float*)(base + WS_DCO);
    float* snorm   = (float*)(base + WS_SNORM);
    __hip_bfloat16* wfmt = (__hip_bfloat16*)(base + WS_WFMT);
    char* xm       = base + WS_XM;
    float* hA      = (float*)(base + WS_HA);
    float* hB      = (float*)(base + WS_HB);
    float* sty     = (float*)(base + WS_STY);

    void* args[] = {
        (void*)&x, (void*)&lat, (void*)&weight, (void*)&wsm, (void*)&bsm,
        (void*)&wff, (void*)&bff, (void*)&wfmt, (void*)&mw2, (void*)&snorm,
        (void*)&dco, (void*)&zerobuf, (void*)&xm, (void*)&hA, (void*)&hB, (void*)&sty
    };
    hipLaunchCooperativeKernel((void*)prep_kernel, dim3(256), dim3(256), args, 0, stream);
    mconv_kernel<<<dim3(8, 4, NB), 512, 0, stream>>>(xm, (const char*)wfmt, dco, zerobuf, y);
}

// Round 6
// 119.309 us; speedup vs baseline: 2.7255x; 2.7255x over previous
//
#include <hip/hip_runtime.h>
#include <hip/hip_bf16.h>

#define LATN 512
#define FINN 256
#define FOUTN 256
#define NB 16
#define HH 64
#define WW 64

typedef __attribute__((ext_vector_type(8))) short bf16x8;
typedef __attribute__((ext_vector_type(4))) float f32x4;
typedef __attribute__((ext_vector_type(4))) int i32x4;

// ------- workspace byte offsets -------
#define WS_ZERO   0           // 256 B
#define WS_MW2    4096        // 256*256*4 = 262144
#define WS_DCO    266240      // 16*256*4  = 16384
#define WS_SNORM  282624      // 16*256*4  = 16384
#define WS_WFMT   299008      // 4*294912  = 1179648
#define WS_XM     1478656     // 16*2097152 = 33554432
// style ping-pong buffers ALIAS the xm region (dead until xcvt runs):
#define WS_HA     (WS_XM)            // 16*512*4
#define WS_HB     (WS_XM + 32768)    // 16*512*4
#define WS_STY    (WS_XM + 65536)    // 16*256*4
// xm layout  : [b][chunk(8)][pos(4096)][slot(4)] granules of 16B (8 bf16 ch), slot = iq ^ sigma(h,w)
// wfmt layout: [obi(4)][chunk(8)][tap(9)][ol(64)][slot(4)] granules, slot = iq ^ ((ol>>1)&3)

// ================= weight prep: swizzled wfmt + mw2 + zerobuf =================
__global__ void weight_prep_kernel(const float* __restrict__ weight,
                                   __hip_bfloat16* __restrict__ wfmt,
                                   float* __restrict__ mw2sum,
                                   float* __restrict__ zerobuf) {
    __shared__ float red[256];
    int o = blockIdx.x, t = threadIdx.x;
    if (o == 0 && t < 64) zerobuf[t] = 0.f;
    const float* wrow = weight + ((size_t)o * FINN + t) * 9;
    float wv[9];
    float mx = 0.f;
    #pragma unroll
    for (int k = 0; k < 9; ++k) { wv[k] = wrow[k]; mx = fmaxf(mx, fabsf(wv[k])); }
    red[t] = mx;
    __syncthreads();
    for (int k = 128; k > 0; k >>= 1) {
        if (t < k) red[t] = fmaxf(red[t], red[t + k]);
        __syncthreads();
    }
    float scale = (1.0f / 48.0f) / red[0];
    int obi = o >> 6, ol = o & 63, ch = t >> 5, il = t & 31;
    int slot = (il >> 3) ^ ((ol >> 1) & 3);
    char* basep = (char*)wfmt + (size_t)obi * 294912 + (size_t)ch * 36864
                + (size_t)ol * 64 + slot * 16 + (il & 7) * 2;
    float s2 = 0.f;
    #pragma unroll
    for (int tap = 0; tap < 9; ++tap) {
        float m = wv[tap] * scale;
        s2 += m * m;
        *(__hip_bfloat16*)(basep + tap * 4096) = __float2bfloat16(m);
    }
    mw2sum[(size_t)o * FINN + t] = s2;
}

// ================= style MLP layer (parallel over j across blocks) =================
// grid = (out_dim/16, B), block = 256. 16 lanes per output j, float4 K-loads.
__global__ __launch_bounds__(256) void style_layer_kernel(
    const float* __restrict__ in, const float* __restrict__ w,
    const float* __restrict__ bias, float* __restrict__ out,
    int in_dim_v4, int out_dim, float scale, int do_lrelu) {
    int t = threadIdx.x;
    int jl = t >> 4, kl = t & 15;
    int j = blockIdx.x * 16 + jl;
    int b = blockIdx.y;
    const float4* inr = (const float4*)(in + (size_t)b * (in_dim_v4 * 4));
    const float4* wr  = (const float4*)(w + (size_t)j * (in_dim_v4 * 4));
    float sum = 0.f;
    #pragma unroll 4
    for (int kb = kl; kb < in_dim_v4; kb += 16) {
        float4 wv = wr[kb], iv = inr[kb];
        sum += wv.x * iv.x + wv.y * iv.y + wv.z * iv.z + wv.w * iv.w;
    }
    #pragma unroll
    for (int off = 8; off >= 1; off >>= 1)
        sum += __shfl_xor(sum, off, 16);
    if (kl == 0) {
        float v = sum * scale + bias[j];
        if (do_lrelu && v < 0.f) v *= 0.2f;
        out[(size_t)b * out_dim + j] = v;
    }
}

// ================= fused inf-norm + dcoef =================
// grid = B, block = 256 (thread = channel/output index)
__global__ __launch_bounds__(256) void norm_dcoef_kernel(
    const float* __restrict__ sty, const float* __restrict__ mw2,
    float* __restrict__ snorm, float* __restrict__ dco) {
    __shared__ float red[256];
    __shared__ float s2[256];
    int b = blockIdx.x, t = threadIdx.x;
    float v = sty[(size_t)b * FINN + t];
    red[t] = fabsf(v);
    __syncthreads();
    for (int k = 128; k > 0; k >>= 1) {
        if (t < k) red[t] = fmaxf(red[t], red[t + k]);
        __syncthreads();
    }
    float sv = v / red[0];
    snorm[(size_t)b * FINN + t] = sv;
    s2[t] = sv * sv;
    __syncthreads();
    const float4* m2 = (const float4*)(mw2 + (size_t)t * FINN);
    const float4* sq = (const float4*)s2;
    float sum = 0.f;
    #pragma unroll 8
    for (int kb = 0; kb < 64; ++kb) {
        float4 a = m2[kb], xq = sq[kb];
        sum += a.x * xq.x + a.y * xq.y + a.z * xq.z + a.w * xq.w;
    }
    dco[(size_t)b * FOUTN + t] = rsqrtf(sum + 1e-8f);
}

// ================= x NCHW fp32 -> swizzled chunk-major bf16 xm =================
// grid (64 h, 16 b), block 256
__global__ __launch_bounds__(256) void xcvt_kernel(const float* __restrict__ x,
                                                   const float* __restrict__ sn,
                                                   char* __restrict__ xm) {
    __shared__ float tile[64][65];
    int h = blockIdx.x, b = blockIdx.y;
    int t = threadIdx.x;
    int wl_ = t & 63, ig = t >> 6;
    char* xmb = xm + (size_t)b * 2097152;
    for (int icb = 0; icb < 4; ++icb) {
        if (icb) __syncthreads();
        #pragma unroll
        for (int p = 0; p < 16; ++p) {
            int i_l = p * 4 + ig;
            int i = icb * 64 + i_l;
            tile[i_l][wl_] = x[((size_t)(b * FINN + i)) * 4096 + h * 64 + wl_]
                             * sn[(size_t)b * FINN + i];
        }
        __syncthreads();
        #pragma unroll
        for (int rep = 0; rep < 2; ++rep) {
            int g = rep * 256 + t;     // 0..511
            int w = g >> 3, q8 = g & 7;
            int chunk = icb * 2 + (q8 >> 2), iq = q8 & 3;
            int slot = iq ^ (((h + 1) + ((w + 1) >> 1)) & 3);
            short tmp[8];
            #pragma unroll
            for (int j = 0; j < 8; ++j) {
                __hip_bfloat16 hb = __float2bfloat16(tile[q8 * 8 + j][w]);
                tmp[j] = *(short*)&hb;
            }
            char* dst = xmb + (size_t)chunk * 262144 + (size_t)(h * 64 + w) * 64 + slot * 16;
            *(bf16x8*)dst = *(bf16x8*)tmp;
        }
    }
}

// ================= global_load_lds helper =================
__device__ __forceinline__ void gl_lds16(const void* g, void* l) {
    __builtin_amdgcn_global_load_lds(
        (const __attribute__((address_space(1))) unsigned int*)g,
        (__attribute__((address_space(3))) unsigned int*)l, 16, 0, 0);
}

// ================= MFMA conv, double-buffered 2-phase schedule =================
// grid (8 htile, 4 obi, 16 b), 512 threads (8 waves).
__global__ __launch_bounds__(512, 2) void mconv_kernel(
    const char* __restrict__ xm, const char* __restrict__ wfmt,
    const float* __restrict__ dco, const float* __restrict__ zerobuf,
    float* __restrict__ y) {
    __shared__ char xs[2][42240];   // 10 rows x 66 cols x 64B, swizzled slots
    __shared__ char wl[2][36864];   // [tap 9][o 64][slot 4] granules

    int t = threadIdx.x;
    int lane = t & 63;
    int wid = t >> 6;
    int h0 = blockIdx.x * 8;
    int obi = blockIdx.y;
    int b = blockIdx.z;

    // zero halo columns (c=0, c=65) in BOTH buffers; never overwritten by staging
    if (t < 160) {
        int bufi = t / 80, u = t % 80;
        int r = u >> 3, sub = u & 7;
        int col = (sub >> 2) * 65, slot = sub & 3;
        *(i32x4*)(xs[bufi] + ((r * 66 + col) * 4 + slot) * 16) = (i32x4){0, 0, 0, 0};
    }

    // x staging: 40 issues/chunk (10 rows x 4 quarters), 5 per wave
    const char* xmb = xm + (size_t)b * 2097152;
    const char* xsrc[5];
    unsigned xinc[5];
    unsigned xdst[5];
    #pragma unroll
    for (int q = 0; q < 5; ++q) {
        int idx = wid * 5 + q;
        int r = idx >> 2, quarter = idx & 3;
        int gh = h0 - 1 + r;
        bool v = (gh >= 0) && (gh < HH);
        xsrc[q] = v ? xmb + (size_t)(gh * 64 + quarter * 16) * 64 + lane * 16
                    : (const char*)zerobuf;
        xinc[q] = v ? 262144u : 0u;
        xdst[q] = (unsigned)((r * 66 + 1) * 64 + quarter * 1024);
    }
    const char* wlane = wfmt + (size_t)obi * 294912 + lane * 16;

    f32x4 acc[4][4] = {};
    int l15 = lane & 15, lg = lane >> 4;
    int wfrag = l15 * 64 + ((lg ^ ((l15 >> 1) & 3)) << 4);

    // ---- prologue: stage chunk 0 into buf 0 ----
    #pragma unroll
    for (int q = 0; q < 5; ++q) {
        gl_lds16(xsrc[q], xs[0] + xdst[q]);
        xsrc[q] += xinc[q];
    }
    #pragma unroll
    for (int q = 0; q < 5; ++q) {
        int idx = wid + q * 8;
        if (idx < 36) gl_lds16(wlane + idx * 1024, wl[0] + idx * 1024);
    }
    wlane += 36864;
    asm volatile("s_waitcnt vmcnt(0)" ::: "memory");
    __builtin_amdgcn_s_barrier();
    __builtin_amdgcn_sched_barrier(0);

    for (int ch = 0; ch < 8; ++ch) {
        int cur = ch & 1;
        // issue next-chunk stages into the other buffer (loads stay in flight
        // across the whole compute phase; drained AFTER compute)
        if (ch < 7) {
            #pragma unroll
            for (int q = 0; q < 5; ++q) {
                gl_lds16(xsrc[q], xs[cur ^ 1] + xdst[q]);
                xsrc[q] += xinc[q];
            }
            #pragma unroll
            for (int q = 0; q < 5; ++q) {
                int idx = wid + q * 8;
                if (idx < 36) gl_lds16(wlane + idx * 1024, wl[cur ^ 1] + idx * 1024);
            }
            wlane += 36864;
        }
        const char* xsb = xs[cur];
        const char* wlb = wl[cur];
        __builtin_amdgcn_s_setprio(1);
        #pragma unroll
        for (int kh = 0; kh < 3; ++kh) {
            #pragma unroll
            for (int kw = 0; kw < 3; ++kw) {
                int tap = kh * 3 + kw;
                int pos0 = (wid + kh) * 66 + kw + l15;
                int xb_off = pos0 * 64 + ((lg ^ ((pos0 >> 1) & 3)) << 4);
                bf16x8 bfr[4];
                #pragma unroll
                for (int nt = 0; nt < 4; ++nt)
                    bfr[nt] = *(const bf16x8*)(xsb + xb_off + nt * 1024);
                #pragma unroll
                for (int mt = 0; mt < 4; ++mt) {
                    bf16x8 af = *(const bf16x8*)(wlb + tap * 4096 + mt * 1024 + wfrag);
                    #pragma unroll
                    for (int nt = 0; nt < 4; ++nt)
                        acc[mt][nt] = __builtin_amdgcn_mfma_f32_16x16x32_bf16(
                            af, bfr[nt], acc[mt][nt], 0, 0, 0);
                }
            }
        }
        __builtin_amdgcn_s_setprio(0);
        // drain this iteration's stage-writes (they had the full compute
        // phase to land), then release the buffer we just read
        asm volatile("s_waitcnt vmcnt(0)" ::: "memory");
        __builtin_amdgcn_s_barrier();
        __builtin_amdgcn_sched_barrier(0);
    }

    // epilogue: demod + store
    const float* dcb = dco + (size_t)b * FOUTN + obi * 64;
    float* yb = y + (((size_t)b * FOUTN + obi * 64) * HH + (h0 + wid)) * WW;
    #pragma unroll
    for (int mt = 0; mt < 4; ++mt) {
        #pragma unroll
        for (int j = 0; j < 4; ++j) {
            int o_l = mt * 16 + lg * 4 + j;
            float d = dcb[o_l];
            #pragma unroll
            for (int nt = 0; nt < 4; ++nt)
                yb[(size_t)o_l * 4096 + nt * 16 + l15] = acc[mt][nt][j] * d;
        }
    }
}

extern "C" void kernel_launch(void* const* d_in, const int* in_sizes, int n_in,
                              void* d_out, int out_size, void* d_ws, size_t ws_size,
                              hipStream_t stream) {
    const float* x      = (const float*)d_in[0];
    const float* lat    = (const float*)d_in[1];
    const float* weight = (const float*)d_in[2];
    const float* wsm    = (const float*)d_in[3];
    const float* bsm    = (const float*)d_in[4];
    const float* wff    = (const float*)d_in[5];
    const float* bff    = (const float*)d_in[6];
    float* y = (float*)d_out;

    char* base = (char*)d_ws;
    float* zerobuf = (float*)(base + WS_ZERO);
    float* mw2     = (float*)(base + WS_MW2);
    float* dco     = (float*)(base + WS_DCO);
    float* snorm   = (float*)(base + WS_SNORM);
    __hip_bfloat16* wfmt = (__hip_bfloat16*)(base + WS_WFMT);
    char* xm       = base + WS_XM;
    float* hA      = (float*)(base + WS_HA);
    float* hB      = (float*)(base + WS_HB);
    float* sty     = (float*)(base + WS_STY);

    const float eq = 0.044194173824159216f;  // 1/sqrt(512)

    weight_prep_kernel<<<FOUTN, 256, 0, stream>>>(weight, wfmt, mw2, zerobuf);
    // style MLP: 4 EqualLinear+LeakyReLU (parallel over j), then final linear
    style_layer_kernel<<<dim3(LATN / 16, NB), 256, 0, stream>>>(
        lat, wsm + 0 * (size_t)LATN * LATN, bsm + 0 * LATN, hA, LATN / 4, LATN, eq, 1);
    style_layer_kernel<<<dim3(LATN / 16, NB), 256, 0, stream>>>(
        hA, wsm + 1 * (size_t)LATN * LATN, bsm + 1 * LATN, hB, LATN / 4, LATN, eq, 1);
    style_layer_kernel<<<dim3(LATN / 16, NB), 256, 0, stream>>>(
        hB, wsm + 2 * (size_t)LATN * LATN, bsm + 2 * LATN, hA, LATN / 4, LATN, eq, 1);
    style_layer_kernel<<<dim3(LATN / 16, NB), 256, 0, stream>>>(
        hA, wsm + 3 * (size_t)LATN * LATN, bsm + 3 * LATN, hB, LATN / 4, LATN, eq, 1);
    style_layer_kernel<<<dim3(FINN / 16, NB), 256, 0, stream>>>(
        hB, wff, bff, sty, LATN / 4, FINN, 1.0f, 0);
    // inf-norm + dcoef (style ping-pong buffers are dead after this point)
    norm_dcoef_kernel<<<NB, 256, 0, stream>>>(sty, mw2, snorm, dco);
    // x conversion (overwrites the aliased style buffers — safe now)
    xcvt_kernel<<<dim3(HH, NB), 256, 0, stream>>>(x, snorm, xm);
    // MFMA conv
    mconv_kernel<<<dim3(8, 4, NB), 512, 0, stream>>>(xm, (const char*)wfmt, dco, zerobuf, y);
}

// Round 7
// 118.230 us; speedup vs baseline: 2.7503x; 1.0091x over previous
//
#include <hip/hip_runtime.h>
#include <hip/hip_bf16.h>

#define LATN 512
#define FINN 256
#define FOUTN 256
#define NB 16
#define HH 64
#define WW 64

typedef __attribute__((ext_vector_type(8))) short bf16x8;
typedef __attribute__((ext_vector_type(4))) float f32x4;
typedef __attribute__((ext_vector_type(4))) int i32x4;

// ------- workspace byte offsets -------
#define WS_ZERO   0           // 256 B
#define WS_MW2    4096        // 256*256*4 = 262144
#define WS_DCO    266240      // 16*256*4  = 16384
#define WS_SNORM  282624      // 16*256*4  = 16384
#define WS_WFMT   299008      // 4*294912  = 1179648
#define WS_XM     1478656     // 16*2097152 = 33554432
// style ping-pong buffers ALIAS the xm region (dead until xcvt runs):
#define WS_HA     (WS_XM)            // 16*512*4
#define WS_HB     (WS_XM + 32768)    // 16*512*4
#define WS_STY    (WS_XM + 65536)    // 16*256*4
// xm layout  : [b][chunk(8)][pos(4096)][slot(4)] granules of 16B (8 bf16 ch), slot = iq ^ sigma(h,w)
// wfmt layout: [obi(4)][chunk(8)][tap(9)][ol(64)][slot(4)] granules, slot = iq ^ ((ol>>1)&3)

// ================= weight prep: swizzled wfmt + mw2 + zerobuf =================
__global__ void weight_prep_kernel(const float* __restrict__ weight,
                                   __hip_bfloat16* __restrict__ wfmt,
                                   float* __restrict__ mw2sum,
                                   float* __restrict__ zerobuf) {
    __shared__ float red[256];
    int o = blockIdx.x, t = threadIdx.x;
    if (o == 0 && t < 64) zerobuf[t] = 0.f;
    const float* wrow = weight + ((size_t)o * FINN + t) * 9;
    float wv[9];
    float mx = 0.f;
    #pragma unroll
    for (int k = 0; k < 9; ++k) { wv[k] = wrow[k]; mx = fmaxf(mx, fabsf(wv[k])); }
    red[t] = mx;
    __syncthreads();
    for (int k = 128; k > 0; k >>= 1) {
        if (t < k) red[t] = fmaxf(red[t], red[t + k]);
        __syncthreads();
    }
    float scale = (1.0f / 48.0f) / red[0];
    int obi = o >> 6, ol = o & 63, ch = t >> 5, il = t & 31;
    int slot = (il >> 3) ^ ((ol >> 1) & 3);
    char* basep = (char*)wfmt + (size_t)obi * 294912 + (size_t)ch * 36864
                + (size_t)ol * 64 + slot * 16 + (il & 7) * 2;
    float s2 = 0.f;
    #pragma unroll
    for (int tap = 0; tap < 9; ++tap) {
        float m = wv[tap] * scale;
        s2 += m * m;
        *(__hip_bfloat16*)(basep + tap * 4096) = __float2bfloat16(m);
    }
    mw2sum[(size_t)o * FINN + t] = s2;
}

// ================= style MLP layer (parallel over j across blocks) =================
__global__ __launch_bounds__(256) void style_layer_kernel(
    const float* __restrict__ in, const float* __restrict__ w,
    const float* __restrict__ bias, float* __restrict__ out,
    int in_dim_v4, int out_dim, float scale, int do_lrelu) {
    int t = threadIdx.x;
    int jl = t >> 4, kl = t & 15;
    int j = blockIdx.x * 16 + jl;
    int b = blockIdx.y;
    const float4* inr = (const float4*)(in + (size_t)b * (in_dim_v4 * 4));
    const float4* wr  = (const float4*)(w + (size_t)j * (in_dim_v4 * 4));
    float sum = 0.f;
    #pragma unroll 4
    for (int kb = kl; kb < in_dim_v4; kb += 16) {
        float4 wv = wr[kb], iv = inr[kb];
        sum += wv.x * iv.x + wv.y * iv.y + wv.z * iv.z + wv.w * iv.w;
    }
    #pragma unroll
    for (int off = 8; off >= 1; off >>= 1)
        sum += __shfl_xor(sum, off, 16);
    if (kl == 0) {
        float v = sum * scale + bias[j];
        if (do_lrelu && v < 0.f) v *= 0.2f;
        out[(size_t)b * out_dim + j] = v;
    }
}

// ================= fused inf-norm + dcoef =================
__global__ __launch_bounds__(256) void norm_dcoef_kernel(
    const float* __restrict__ sty, const float* __restrict__ mw2,
    float* __restrict__ snorm, float* __restrict__ dco) {
    __shared__ float red[256];
    __shared__ float s2[256];
    int b = blockIdx.x, t = threadIdx.x;
    float v = sty[(size_t)b * FINN + t];
    red[t] = fabsf(v);
    __syncthreads();
    for (int k = 128; k > 0; k >>= 1) {
        if (t < k) red[t] = fmaxf(red[t], red[t + k]);
        __syncthreads();
    }
    float sv = v / red[0];
    snorm[(size_t)b * FINN + t] = sv;
    s2[t] = sv * sv;
    __syncthreads();
    const float4* m2 = (const float4*)(mw2 + (size_t)t * FINN);
    const float4* sq = (const float4*)s2;
    float sum = 0.f;
    #pragma unroll 8
    for (int kb = 0; kb < 64; ++kb) {
        float4 a = m2[kb], xq = sq[kb];
        sum += a.x * xq.x + a.y * xq.y + a.z * xq.z + a.w * xq.w;
    }
    dco[(size_t)b * FOUTN + t] = rsqrtf(sum + 1e-8f);
}

// ================= x NCHW fp32 -> swizzled chunk-major bf16 xm =================
__global__ __launch_bounds__(256) void xcvt_kernel(const float* __restrict__ x,
                                                   const float* __restrict__ sn,
                                                   char* __restrict__ xm) {
    __shared__ float tile[64][65];
    int h = blockIdx.x, b = blockIdx.y;
    int t = threadIdx.x;
    int wl_ = t & 63, ig = t >> 6;
    char* xmb = xm + (size_t)b * 2097152;
    for (int icb = 0; icb < 4; ++icb) {
        if (icb) __syncthreads();
        #pragma unroll
        for (int p = 0; p < 16; ++p) {
            int i_l = p * 4 + ig;
            int i = icb * 64 + i_l;
            tile[i_l][wl_] = x[((size_t)(b * FINN + i)) * 4096 + h * 64 + wl_]
                             * sn[(size_t)b * FINN + i];
        }
        __syncthreads();
        #pragma unroll
        for (int rep = 0; rep < 2; ++rep) {
            int g = rep * 256 + t;     // 0..511
            int w = g >> 3, q8 = g & 7;
            int chunk = icb * 2 + (q8 >> 2), iq = q8 & 3;
            int slot = iq ^ (((h + 1) + ((w + 1) >> 1)) & 3);
            short tmp[8];
            #pragma unroll
            for (int j = 0; j < 8; ++j) {
                __hip_bfloat16 hb = __float2bfloat16(tile[q8 * 8 + j][w]);
                tmp[j] = *(short*)&hb;
            }
            char* dst = xmb + (size_t)chunk * 262144 + (size_t)(h * 64 + w) * 64 + slot * 16;
            *(bf16x8*)dst = *(bf16x8*)tmp;
        }
    }
}

// ================= global_load_lds helper =================
__device__ __forceinline__ void gl_lds16(const void* g, void* l) {
    __builtin_amdgcn_global_load_lds(
        (const __attribute__((address_space(1))) unsigned int*)g,
        (__attribute__((address_space(3))) unsigned int*)l, 16, 0, 0);
}

// ---- fragment helpers (fully inlined; all indices static after unroll) ----
__device__ __forceinline__ void rd_tap(bf16x8* xf, bf16x8* wf,
                                       const char* xsb, const char* wlb,
                                       int wid, int l15, int lg, int wfrag,
                                       int kh, int kw) {
    int tap = kh * 3 + kw;
    int pos0 = (wid + kh) * 66 + kw + l15;
    int xoff = pos0 * 64 + ((lg ^ ((pos0 >> 1) & 3)) << 4);
    #pragma unroll
    for (int nt = 0; nt < 4; ++nt)
        xf[nt] = *(const bf16x8*)(xsb + xoff + nt * 1024);
    #pragma unroll
    for (int mt = 0; mt < 4; ++mt)
        wf[mt] = *(const bf16x8*)(wlb + tap * 4096 + mt * 1024 + wfrag);
}

__device__ __forceinline__ void mm_tap(f32x4 acc[4][4], const bf16x8* xf, const bf16x8* wf) {
    #pragma unroll
    for (int mt = 0; mt < 4; ++mt)
        #pragma unroll
        for (int nt = 0; nt < 4; ++nt)
            acc[mt][nt] = __builtin_amdgcn_mfma_f32_16x16x32_bf16(
                wf[mt], xf[nt], acc[mt][nt], 0, 0, 0);
}

// pipelined step: read next tap's frags, wait for current tap's frags, MFMA current
#define STEP(XFN, WFN, KH, KW, XFC, WFC)                                \
    rd_tap(XFN, WFN, xsb, wlb, wid, l15, lg, wfrag, KH, KW);            \
    __builtin_amdgcn_sched_barrier(0);                                  \
    asm volatile("s_waitcnt lgkmcnt(8)" ::: "memory");                  \
    __builtin_amdgcn_sched_barrier(0);                                  \
    __builtin_amdgcn_s_setprio(1);                                      \
    mm_tap(acc, XFC, WFC);                                              \
    __builtin_amdgcn_s_setprio(0);

// ================= MFMA conv, dbuf + tap-level software pipeline =================
// grid (8 htile, 4 obi, 16 b), 512 threads (8 waves).
__global__ __launch_bounds__(512, 2) void mconv_kernel(
    const char* __restrict__ xm, const char* __restrict__ wfmt,
    const float* __restrict__ dco, const float* __restrict__ zerobuf,
    float* __restrict__ y) {
    __shared__ char xs[2][42240];   // 10 rows x 66 cols x 64B, swizzled slots
    __shared__ char wl[2][36864];   // [tap 9][o 64][slot 4] granules

    int t = threadIdx.x;
    int lane = t & 63;
    int wid = t >> 6;
    int h0 = blockIdx.x * 8;
    int obi = blockIdx.y;
    int b = blockIdx.z;

    // zero halo columns (c=0, c=65) in BOTH buffers; never overwritten by staging
    if (t < 160) {
        int bufi = t / 80, u = t % 80;
        int r = u >> 3, sub = u & 7;
        int col = (sub >> 2) * 65, slot = sub & 3;
        *(i32x4*)(xs[bufi] + ((r * 66 + col) * 4 + slot) * 16) = (i32x4){0, 0, 0, 0};
    }

    // x staging: 40 issues/chunk (10 rows x 4 quarters), 5 per wave
    const char* xmb = xm + (size_t)b * 2097152;
    const char* xsrc[5];
    unsigned xinc[5];
    unsigned xdst[5];
    #pragma unroll
    for (int q = 0; q < 5; ++q) {
        int idx = wid * 5 + q;
        int r = idx >> 2, quarter = idx & 3;
        int gh = h0 - 1 + r;
        bool v = (gh >= 0) && (gh < HH);
        xsrc[q] = v ? xmb + (size_t)(gh * 64 + quarter * 16) * 64 + lane * 16
                    : (const char*)zerobuf;
        xinc[q] = v ? 262144u : 0u;
        xdst[q] = (unsigned)((r * 66 + 1) * 64 + quarter * 1024);
    }
    const char* wlane = wfmt + (size_t)obi * 294912 + lane * 16;

    f32x4 acc[4][4] = {};
    int l15 = lane & 15, lg = lane >> 4;
    int wfrag = l15 * 64 + ((lg ^ ((l15 >> 1) & 3)) << 4);

    // ---- prologue: stage chunk 0 into buf 0 ----
    #pragma unroll
    for (int q = 0; q < 5; ++q) {
        gl_lds16(xsrc[q], xs[0] + xdst[q]);
        xsrc[q] += xinc[q];
    }
    #pragma unroll
    for (int q = 0; q < 5; ++q) {
        int idx = wid + q * 8;
        if (idx < 36) gl_lds16(wlane + idx * 1024, wl[0] + idx * 1024);
    }
    wlane += 36864;
    asm volatile("s_waitcnt vmcnt(0)" ::: "memory");
    __builtin_amdgcn_s_barrier();
    __builtin_amdgcn_sched_barrier(0);

    for (int ch = 0; ch < 8; ++ch) {
        int cur = ch & 1;
        // issue next-chunk stages into the other buffer (in flight across compute)
        if (ch < 7) {
            #pragma unroll
            for (int q = 0; q < 5; ++q) {
                gl_lds16(xsrc[q], xs[cur ^ 1] + xdst[q]);
                xsrc[q] += xinc[q];
            }
            #pragma unroll
            for (int q = 0; q < 5; ++q) {
                int idx = wid + q * 8;
                if (idx < 36) gl_lds16(wlane + idx * 1024, wl[cur ^ 1] + idx * 1024);
            }
            wlane += 36864;
        }
        const char* xsb = xs[cur];
        const char* wlb = wl[cur];

        // ---- tap-level software pipeline: 2 frag banks, counted lgkm waits ----
        bf16x8 xf0[4], wf0[4], xf1[4], wf1[4];
        rd_tap(xf0, wf0, xsb, wlb, wid, l15, lg, wfrag, 0, 0);
        STEP(xf1, wf1, 0, 1, xf0, wf0)
        STEP(xf0, wf0, 0, 2, xf1, wf1)
        STEP(xf1, wf1, 1, 0, xf0, wf0)
        STEP(xf0, wf0, 1, 1, xf1, wf1)
        STEP(xf1, wf1, 1, 2, xf0, wf0)
        STEP(xf0, wf0, 2, 0, xf1, wf1)
        STEP(xf1, wf1, 2, 1, xf0, wf0)
        STEP(xf0, wf0, 2, 2, xf1, wf1)
        __builtin_amdgcn_sched_barrier(0);
        asm volatile("s_waitcnt lgkmcnt(0)" ::: "memory");
        __builtin_amdgcn_sched_barrier(0);
        __builtin_amdgcn_s_setprio(1);
        mm_tap(acc, xf0, wf0);
        __builtin_amdgcn_s_setprio(0);

        // drain this iteration's stage-writes, then release the buffer just read
        asm volatile("s_waitcnt vmcnt(0)" ::: "memory");
        __builtin_amdgcn_s_barrier();
        __builtin_amdgcn_sched_barrier(0);
    }

    // epilogue: demod + store
    const float* dcb = dco + (size_t)b * FOUTN + obi * 64;
    float* yb = y + (((size_t)b * FOUTN + obi * 64) * HH + (h0 + wid)) * WW;
    #pragma unroll
    for (int mt = 0; mt < 4; ++mt) {
        #pragma unroll
        for (int j = 0; j < 4; ++j) {
            int o_l = mt * 16 + lg * 4 + j;
            float d = dcb[o_l];
            #pragma unroll
            for (int nt = 0; nt < 4; ++nt)
                yb[(size_t)o_l * 4096 + nt * 16 + l15] = acc[mt][nt][j] * d;
        }
    }
}

extern "C" void kernel_launch(void* const* d_in, const int* in_sizes, int n_in,
                              void* d_out, int out_size, void* d_ws, size_t ws_size,
                              hipStream_t stream) {
    const float* x      = (const float*)d_in[0];
    const float* lat    = (const float*)d_in[1];
    const float* weight = (const float*)d_in[2];
    const float* wsm    = (const float*)d_in[3];
    const float* bsm    = (const float*)d_in[4];
    const float* wff    = (const float*)d_in[5];
    const float* bff    = (const float*)d_in[6];
    float* y = (float*)d_out;

    char* base = (char*)d_ws;
    float* zerobuf = (float*)(base + WS_ZERO);
    float* mw2     = (float*)(base + WS_MW2);
    float* dco     = (float*)(base + WS_DCO);
    float* snorm   = (float*)(base + WS_SNORM);
    __hip_bfloat16* wfmt = (__hip_bfloat16*)(base + WS_WFMT);
    char* xm       = base + WS_XM;
    float* hA      = (float*)(base + WS_HA);
    float* hB      = (float*)(base + WS_HB);
    float* sty     = (float*)(base + WS_STY);

    const float eq = 0.044194173824159216f;  // 1/sqrt(512)

    weight_prep_kernel<<<FOUTN, 256, 0, stream>>>(weight, wfmt, mw2, zerobuf);
    style_layer_kernel<<<dim3(LATN / 16, NB), 256, 0, stream>>>(
        lat, wsm + 0 * (size_t)LATN * LATN, bsm + 0 * LATN, hA, LATN / 4, LATN, eq, 1);
    style_layer_kernel<<<dim3(LATN / 16, NB), 256, 0, stream>>>(
        hA, wsm + 1 * (size_t)LATN * LATN, bsm + 1 * LATN, hB, LATN / 4, LATN, eq, 1);
    style_layer_kernel<<<dim3(LATN / 16, NB), 256, 0, stream>>>(
        hB, wsm + 2 * (size_t)LATN * LATN, bsm + 2 * LATN, hA, LATN / 4, LATN, eq, 1);
    style_layer_kernel<<<dim3(LATN / 16, NB), 256, 0, stream>>>(
        hA, wsm + 3 * (size_t)LATN * LATN, bsm + 3 * LATN, hB, LATN / 4, LATN, eq, 1);
    style_layer_kernel<<<dim3(FINN / 16, NB), 256, 0, stream>>>(
        hB, wff, bff, sty, LATN / 4, FINN, 1.0f, 0);
    norm_dcoef_kernel<<<NB, 256, 0, stream>>>(sty, mw2, snorm, dco);
    xcvt_kernel<<<dim3(HH, NB), 256, 0, stream>>>(x, snorm, xm);
    mconv_kernel<<<dim3(8, 4, NB), 512, 0, stream>>>(xm, (const char*)wfmt, dco, zerobuf, y);
}